// Round 4
// baseline (651.420 us; speedup 1.0000x reference)
//
#include <hip/hip_runtime.h>
#include <math.h>

// Problem constants
#define NN   2048
#define EE   8192
#define CNF  256
#define MN   16384
#define ME   65536
#define KK   1024

// Output layout (float element offsets)
#define OUT_XN   ((size_t)0)
#define OUT_L0   ((size_t)262144)
#define OUT_XE   ((size_t)1310720)
#define OUT_L1   ((size_t)3407872)
#define OUT_PM   ((size_t)70516736)
#define OUT_XN0  ((size_t)78905344)
#define OUT_XE0  ((size_t)79167488)

// Workspace layout (element offsets)
#define WS_T1N    0
#define WS_SLINN  2048
#define WS_T1E    4096
#define WS_SLINE  12288
#define WS_SCN    20480
#define WS_SCE    22528
#define WS_JOINT  30720
#define WS_AGGN   32768
#define WS_AGGE   34816
#define WS_LAM    43008
#define WS_IDXK   43520
#define WS_RANK   44544
#define WS_DEG    46592
#define WS_OFFS   47616
#define WS_CUR    48768
#define WS_ADJO   49792   // int[16384]
#define WS_ADJE   66176   // int[16384]
#define WS_KEEPE  82560   // int[8192]
#define WS_BARS   90752   // [gcnt, ggen, ccnt, cgen]
#define WS_END    90756   // divisible by 4

#define GRID_B   224
#define CHAIN_B  64
#define ZERO_B   (GRID_B - CHAIN_B)

// ------------------------------------------------ ws zero (barrier init)
__global__ void k_zero_ws(float* __restrict__ ws) {
    int i = blockIdx.x * blockDim.x + threadIdx.x;
    int n4 = WS_END / 4;
    float4 z = make_float4(0.f, 0.f, 0.f, 0.f);
    float4* w = (float4*)ws;
    for (int p = i; p < n4; p += gridDim.x * blockDim.x) w[p] = z;
}

// ---------------------------------------- sense-reversing global barrier
// cnt/gen zeroed by k_zero_ws each call. Agent-scope acq_rel gives the
// cross-XCD happens-before (per-XCD L2s are not coherent otherwise).
__device__ __forceinline__ void dev_barrier(int* cnt, int* gen, int nb) {
    __syncthreads();
    if (threadIdx.x == 0) {
        int g = __hip_atomic_load(gen, __ATOMIC_RELAXED, __HIP_MEMORY_SCOPE_AGENT);
        int old = __hip_atomic_fetch_add(cnt, 1, __ATOMIC_ACQ_REL, __HIP_MEMORY_SCOPE_AGENT);
        if (old == nb - 1) {
            __hip_atomic_store(cnt, 0, __ATOMIC_RELAXED, __HIP_MEMORY_SCOPE_AGENT);
            __hip_atomic_fetch_add(gen, 1, __ATOMIC_ACQ_REL, __HIP_MEMORY_SCOPE_AGENT);
        } else {
            while (__hip_atomic_load(gen, __ATOMIC_ACQUIRE, __HIP_MEMORY_SCOPE_AGENT) == g)
                __builtin_amdgcn_s_sleep(2);
        }
    }
    __syncthreads();
}

// --------------------------------------------------- block reduce (16 waves)
__device__ __forceinline__ float block_reduce_sum(float val, float* red) {
    #pragma unroll
    for (int o = 32; o > 0; o >>= 1) val += __shfl_down(val, o, 64);
    int lane = threadIdx.x & 63, wid = threadIdx.x >> 6;
    if (lane == 0) red[wid] = val;
    __syncthreads();
    float r = 0.0f;
    if (threadIdx.x < 16) {
        r = red[threadIdx.x];
        #pragma unroll
        for (int o = 8; o > 0; o >>= 1) r += __shfl_down(r, o, 16);
        if (threadIdx.x == 0) red[0] = r;
    }
    __syncthreads();
    float out = red[0];
    __syncthreads();
    return out;
}

#define DCAP 8
#define PWR_T 96

// =====================================================================
// Fused kernel: blocks [0,64) run the serial ws-only chain with a
// 64-block barrier; blocks [64,224) zero the 325 MB output meanwhile.
// One grid barrier, then all blocks write PM/L0/L1/gathers (2/lam folded).
// All 224 blocks co-resident: 1024 thr (16 waves), ~17 KB LDS, <=128 VGPR.
// =====================================================================
__global__ __launch_bounds__(1024) void k_fused(
        const float* __restrict__ xn, const int* __restrict__ ein,
        const float* __restrict__ ewn, const float* __restrict__ xe,
        const int* __restrict__ eie, const float* __restrict__ ewe,
        const int* __restrict__ ei, const float* __restrict__ xn0,
        const float* __restrict__ xe0,
        const float* __restrict__ Wn0, const float* __restrict__ Wn1,
        const float* __restrict__ bn, const float* __restrict__ We0,
        const float* __restrict__ We1, const float* __restrict__ be,
        float* __restrict__ out, float* __restrict__ wsf,
        int* __restrict__ wsi, size_t out_elems) {
    __shared__ unsigned long long s_u64[2048];   // 16 KB: topk keys / scan ints / power v
    __shared__ float s_red[16];
    int bid = blockIdx.x, tid = threadIdx.x;
    int* gcnt = wsi + WS_BARS + 0; int* ggen = wsi + WS_BARS + 1;
    int* ccnt = wsi + WS_BARS + 2; int* cgen = wsi + WS_BARS + 3;

    if (bid >= CHAIN_B) {
        // ---------------- zeroer blocks: clear entire output buffer ----------------
        size_t f4 = out_elems / 4;
        float4* o4 = (float4*)out;
        float4 z = make_float4(0.f, 0.f, 0.f, 0.f);
        size_t start = (size_t)(bid - CHAIN_B) * 1024 + tid;
        size_t stride = (size_t)ZERO_B * 1024;
        for (size_t p = start; p < f4; p += stride) o4[p] = z;
    } else {
        // ---------------- chain blocks (64 blocks, 65536 threads) ----------------
        int ct = bid * 1024 + tid;              // 0..65535
        int gw = bid * 16 + (tid >> 6);         // global wave 0..1023
        int lane = tid & 63;

        // P1: row dots (wave per row, 10 rows/wave)
        for (int row = gw; row < NN + EE; row += 1024) {
            const float *x, *W0, *W1; float *t1, *sl; int r;
            if (row < NN) { r = row;      x = xn + (size_t)r * CNF; W0 = Wn0; W1 = Wn1; t1 = wsf + WS_T1N; sl = wsf + WS_SLINN; }
            else          { r = row - NN; x = xe + (size_t)r * CNF; W0 = We0; W1 = We1; t1 = wsf + WS_T1E; sl = wsf + WS_SLINE; }
            float4 xv = ((const float4*)x)[lane];
            float4 w0 = ((const float4*)W0)[lane];
            float4 w1 = ((const float4*)W1)[lane];
            float d0 = xv.x*w0.x + xv.y*w0.y + xv.z*w0.z + xv.w*w0.w;
            float d1 = xv.x*w1.x + xv.y*w1.y + xv.z*w1.z + xv.w*w1.w;
            #pragma unroll
            for (int o = 32; o > 0; o >>= 1) { d0 += __shfl_down(d0, o, 64); d1 += __shfl_down(d1, o, 64); }
            if (lane == 0) { t1[r] = d1; sl[r] = d0 + d1; }
        }
        dev_barrier(ccnt, cgen, CHAIN_B);

        // P2: conv-edge scatter
        if (ct < MN) {
            int s = ein[ct], d = ein[MN + ct];
            atomicAdd(wsf + WS_AGGN + d, ewn[ct] * wsf[WS_T1N + s]);
        }
        {
            int s = eie[ct], d = eie[ME + ct];   // ct covers [0,65536) exactly
            atomicAdd(wsf + WS_AGGE + d, ewe[ct] * wsf[WS_T1E + s]);
        }
        dev_barrier(ccnt, cgen, CHAIN_B);

        // P3: sigmoid scores
        if (ct < NN) {
            float zv = wsf[WS_SLINN + ct] - wsf[WS_AGGN + ct] + bn[0];
            float s = 1.0f / (1.0f + expf(-zv));
            wsf[WS_SCN + ct] = s;
            wsf[WS_JOINT + ct] = s;
        } else if (ct < NN + EE) {
            int j = ct - NN;
            float zv = wsf[WS_SLINE + j] - wsf[WS_AGGE + j] + be[0];
            wsf[WS_SCE + j] = 1.0f / (1.0f + expf(-zv));
        }
        dev_barrier(ccnt, cgen, CHAIN_B);

        // P4: joint node score
        if (ct < EE) {
            float v = 0.125f * wsf[WS_SCE + ct];
            atomicAdd(wsf + WS_JOINT + ei[ct], v);
            atomicAdd(wsf + WS_JOINT + ei[EE + ct], v);
        }
        dev_barrier(ccnt, cgen, CHAIN_B);

        // P5: top-K (block 0): bitonic sort 2048 keys, then flag+scan ranks
        if (bid == 0) {
            for (int i = tid; i < 2048; i += 1024) {
                float f = wsf[WS_JOINT + i];
                unsigned u = __float_as_uint(f);
                unsigned sk = (u & 0x80000000u) ? ~u : (u | 0x80000000u);
                s_u64[i] = (((unsigned long long)(~sk)) << 32) | (unsigned)i;
            }
            __syncthreads();
            for (int k = 2; k <= 2048; k <<= 1) {
                for (int j = k >> 1; j >= 1; j >>= 1) {
                    for (int i = tid; i < 2048; i += 1024) {
                        int ixj = i ^ j;
                        if (ixj > i) {
                            bool up = ((i & k) == 0);
                            unsigned long long a = s_u64[i], b = s_u64[ixj];
                            if ((a > b) == up) { s_u64[i] = b; s_u64[ixj] = a; }
                        }
                    }
                    __syncthreads();
                }
            }
            int myid = (int)(s_u64[tid] & 0xFFFFFFFFu);   // top-1024 ids
            __syncthreads();
            int* s_i = (int*)s_u64;
            s_i[tid] = 0; s_i[tid + 1024] = 0; s_i[tid + 2048] = 0;
            __syncthreads();
            s_i[myid] = 1;                                 // kept flags [0,2048)
            __syncthreads();
            int a0 = s_i[2 * tid], a1 = s_i[2 * tid + 1];
            int pairsum = a0 + a1;
            s_i[2048 + tid] = pairsum;
            __syncthreads();
            for (int off = 1; off < 1024; off <<= 1) {
                int v = (tid >= off) ? s_i[2048 + tid - off] : 0;
                __syncthreads();
                s_i[2048 + tid] += v;
                __syncthreads();
            }
            int excl = s_i[2048 + tid] - pairsum;
            int i0 = 2 * tid, i1 = 2 * tid + 1;
            int r0 = excl, r1 = excl + a0;
            wsi[WS_RANK + i0] = a0 ? r0 : -1;
            wsi[WS_RANK + i1] = a1 ? r1 : -1;
            if (a0) wsi[WS_IDXK + r0] = i0;
            if (a1) wsi[WS_IDXK + r1] = i1;
        }
        dev_barrier(ccnt, cgen, CHAIN_B);

        // P6: degrees + keep_e flags
        if (ct < EE) {
            int s = ei[ct], d = ei[EE + ct];
            int rs = wsi[WS_RANK + s], rd = wsi[WS_RANK + d];
            wsi[WS_KEEPE + ct] = (rs >= 0 && rd >= 0) ? 1 : 0;
            if (rs >= 0 && rd >= 0 && s != d) {
                atomicAdd(wsi + WS_DEG + rs, 1);
                atomicAdd(wsi + WS_DEG + rd, 1);
            }
        }
        dev_barrier(ccnt, cgen, CHAIN_B);

        // P7: CSR offsets (block 0)
        if (bid == 0) {
            int* s_i = (int*)s_u64;
            int dg = wsi[WS_DEG + tid];
            s_i[tid] = dg;
            for (int off = 1; off < 1024; off <<= 1) {
                __syncthreads();
                int v = (tid >= off) ? s_i[tid - off] : 0;
                __syncthreads();
                s_i[tid] += v;
            }
            __syncthreads();
            wsi[WS_OFFS + tid] = s_i[tid] - dg;
            wsi[WS_CUR + tid]  = s_i[tid] - dg;
            if (tid == 1023) wsi[WS_OFFS + 1024] = s_i[1023];
        }
        dev_barrier(ccnt, cgen, CHAIN_B);

        // P8: CSR fill
        if (ct < EE) {
            int s = ei[ct], d = ei[EE + ct];
            int rs = wsi[WS_RANK + s], rd = wsi[WS_RANK + d];
            if (rs >= 0 && rd >= 0 && s != d) {
                int p = atomicAdd(wsi + WS_CUR + rs, 1);
                wsi[WS_ADJO + p] = rd;
                wsi[WS_ADJE + p] = (ct << 1);
                int q = atomicAdd(wsi + WS_CUR + rd, 1);
                wsi[WS_ADJO + q] = rs;
                wsi[WS_ADJE + q] = (ct << 1) | 1;
            }
        }
        dev_barrier(ccnt, cgen, CHAIN_B);

        // P9: power iteration (block 0); adjacency reg-cached from global, v in LDS
        if (bid == 0) {
            float* v0 = (float*)s_u64;
            float* v1 = v0 + 1024;
            int d  = wsi[WS_DEG + tid];
            int o0 = wsi[WS_OFFS + tid];
            unsigned h = (unsigned)tid * 2654435761u + 911u;
            h ^= h >> 15; h *= 2246822519u; h ^= h >> 13;
            v0[tid] = (float)(h & 0xFFFFu) * (1.0f / 65536.0f) - 0.5f;
            int aj[DCAP];
            #pragma unroll
            for (int j = 0; j < DCAP; ++j) aj[j] = (j < d) ? wsi[WS_ADJO + o0 + j] : 0;
            __syncthreads();
            float* vc = v0; float* vn = v1;
            for (int iter = 0; iter < PWR_T; ++iter) {
                float acc = 0.0f;
                #pragma unroll
                for (int j = 0; j < DCAP; ++j) acc += (j < d) ? vc[aj[j]] : 0.0f;
                for (int i = o0 + DCAP; i < o0 + d; ++i) acc += vc[wsi[WS_ADJO + i]];
                float y = (float)d * vc[tid] - acc;
                if ((iter & 7) == 7) {
                    float n2 = block_reduce_sum(y * y, s_red);
                    y *= (n2 > 0.0f) ? rsqrtf(n2) : 0.0f;
                }
                vn[tid] = y;
                __syncthreads();
                float* tmp = vc; vc = vn; vn = tmp;
            }
            float acc = 0.0f;
            #pragma unroll
            for (int j = 0; j < DCAP; ++j) acc += (j < d) ? vc[aj[j]] : 0.0f;
            for (int i = o0 + DCAP; i < o0 + d; ++i) acc += vc[wsi[WS_ADJO + i]];
            float y = (float)d * vc[tid] - acc;
            float rq = block_reduce_sum(vc[tid] * y, s_red);
            if (tid == 0) wsf[WS_LAM] = rq;
        }
    }

    // ---------------- grid barrier: chain done AND output zeroed ----------------
    dev_barrier(gcnt, ggen, GRID_B);

    // ---------------- final phase (all 224 blocks): out-dependent writes --------
    float sc = 2.0f / wsf[WS_LAM];
    int gt = bid * 1024 + tid;
    int gstr = GRID_B * 1024;

    // (a) kept-node feature gathers
    for (int i = gt; i < KK * 64; i += gstr) {
        int r = i >> 6, c = i & 63;
        int src = wsi[WS_IDXK + r];
        float s = wsf[WS_SCN + src];
        float4 v = ((const float4*)(xn + (size_t)src * CNF))[c];
        v.x *= s; v.y *= s; v.z *= s; v.w *= s;
        ((float4*)(out + OUT_XN))[(size_t)r * 64 + c] = v;
        ((float4*)(out + OUT_XN0))[(size_t)r * 64 + c] = ((const float4*)(xn0 + (size_t)src * CNF))[c];
    }
    // (b) kept-edge feature rows (dropped rows stay zero)
    for (int i = gt; i < EE * 64; i += gstr) {
        int e = i >> 6;
        if (!wsi[WS_KEEPE + e]) continue;
        int c = i & 63;
        float s = wsf[WS_SCE + e];
        float4 v = ((const float4*)(xe + (size_t)e * CNF))[c];
        v.x *= s; v.y *= s; v.z *= s; v.w *= s;
        ((float4*)(out + OUT_XE))[(size_t)e * 64 + c] = v;
        ((float4*)(out + OUT_XE0))[(size_t)e * 64 + c] = ((const float4*)(xe0 + (size_t)e * CNF))[c];
    }
    // (c) par_masked + L0 (2/lam folded into scatter values)
    {
        float* pm = out + OUT_PM;
        float* L0 = out + OUT_L0;
        for (int e = gt; e < EE; e += gstr) {
            int s = ei[e], d = ei[EE + e];
            int rs = wsi[WS_RANK + s], rd = wsi[WS_RANK + d];
            if (rs < 0 || rd < 0 || s == d) continue;
            pm[(size_t)rs * EE + e] = -1.0f;
            pm[(size_t)rd * EE + e] =  1.0f;
            atomicAdd(&L0[(size_t)rs * KK + rs],  sc);
            atomicAdd(&L0[(size_t)rd * KK + rd],  sc);
            atomicAdd(&L0[(size_t)rs * KK + rd], -sc);
            atomicAdd(&L0[(size_t)rd * KK + rs], -sc);
        }
    }
    // (d) L1 scatter: wave per node-row, lanes over inner pairs
    {
        float* L1 = out + OUT_L1;
        int gwv = gt >> 6, lane = gt & 63, wstr = gstr >> 6;
        for (int r = gwv; r < KK; r += wstr) {
            int o0 = wsi[WS_OFFS + r], o1 = wsi[WS_OFFS + r + 1];
            for (int i = o0; i < o1; ++i) {
                int eiv = wsi[WS_ADJE + i];
                int e = eiv >> 1;
                float si = (eiv & 1) ? sc : -sc;
                for (int j = o0 + lane; j < o1; j += 64) {
                    int ejv = wsi[WS_ADJE + j];
                    atomicAdd(&L1[(size_t)e * EE + (ejv >> 1)], (ejv & 1) ? si : -si);
                }
            }
        }
    }
}

extern "C" void kernel_launch(void* const* d_in, const int* in_sizes, int n_in,
                              void* d_out, int out_size, void* d_ws, size_t ws_size,
                              hipStream_t stream) {
    const float* x_n  = (const float*)d_in[0];
    const int*   ei_n = (const int*)  d_in[1];
    const float* ew_n = (const float*)d_in[2];
    const float* x_e  = (const float*)d_in[3];
    const int*   ei_e = (const int*)  d_in[4];
    const float* ew_e = (const float*)d_in[5];
    const int*   ei   = (const int*)  d_in[6];
    const float* x_n0 = (const float*)d_in[9];
    const float* x_e0 = (const float*)d_in[10];
    const float* Wn0  = (const float*)d_in[11];
    const float* Wn1  = (const float*)d_in[12];
    const float* bn   = (const float*)d_in[13];
    const float* We0  = (const float*)d_in[14];
    const float* We1  = (const float*)d_in[15];
    const float* be   = (const float*)d_in[16];

    float* out = (float*)d_out;
    float* wsf = (float*)d_ws;
    int*   wsi = (int*)d_ws;

    k_zero_ws<<<64, 256, 0, stream>>>(wsf);
    k_fused<<<GRID_B, 1024, 0, stream>>>(x_n, ei_n, ew_n, x_e, ei_e, ew_e, ei,
                                         x_n0, x_e0, Wn0, Wn1, bn, We0, We1, be,
                                         out, wsf, wsi, (size_t)out_size);
}